// Round 1
// 267.598 us; speedup vs baseline: 1.1716x; 1.1716x over previous
//
#include <hip/hip_runtime.h>
#include <hip/hip_bf16.h>

// SMPL-X LBS forward. B=512, V=10475, J=55. f32 in/out; fp16 MFMA internally.
//
//  k_sdirs : s_dirs = v_template + shape.shapedirs
//  k_ymin  : y_offset
//  k_jreg  : Js = Jreg@s_dirs, JE = Jreg@exprdirs
//  k_lwT   : lwT packed MFMA-fragment-major [vtile][ks][lane][8]
//  k_batch : Rodrigues -> PFH packed [btile][kc][lane][8]; chain (shfl, no
//            barriers) -> AH packed [b][ks][lane][8]
//  k_pose  : D[n][b] = pdT_tile(LDS) x PFH(packed, coalesced); +s_dirs -> VPH2
//  k_lbs   : T = AH x lwT (packed coalesced frag loads); VPH2 slice staged in
//            LDS; 32m2 x 64v per wave, <=64 VGPR for 8 waves/SIMD

typedef _Float16 f16;
typedef f16  f16x8 __attribute__((ext_vector_type(8)));
typedef f16  f16x4 __attribute__((ext_vector_type(4)));
typedef float f32x4 __attribute__((ext_vector_type(4)));

#define VN    10475
#define JN    55
#define BN    512
#define VC3   31425
#define NPAD  31488          // 492*64
#define VPADV 10496

// f32 ws region (float offsets):
#define SD_F  0              // s_dirs [VC3]
#define JS_F  31425          // [165]
#define JE_F  31590          // [1650]
#define Y_F   33240
// byte offsets:
#define PFH_BYTE  (160*1024)           // f16 packed [32][16][64][8]  = 512 KB
#define AH_BYTE   (768*1024)           // f16 packed [512][2][64][8]  = 1 MB
#define VPH_BYTE  (2*1024*1024)        // f16 [512][31488] = 30.75 MB
#define LWT_BYTE  (34*1024*1024)       // f16 packed [656][2][64][8]  = 1.3 MB

// ---------------- kernel 1 ----------------
__global__ void k_sdirs(const float* __restrict__ vt, const float* __restrict__ shapedirs,
                        const float* __restrict__ shape, float* __restrict__ ws)
{
    int i = blockIdx.x * 256 + threadIdx.x;
    if (i >= VC3) return;
    float acc = vt[i];
    const float* sd = shapedirs + (size_t)i * 10;
    #pragma unroll
    for (int s = 0; s < 10; ++s) acc += shape[s] * sd[s];
    ws[SD_F + i] = acc;
}

// ---------------- kernel 2 ----------------
__global__ void k_ymin(const float* __restrict__ vt, float* __restrict__ ws)
{
    __shared__ float red[256];
    int tid = threadIdx.x;
    float m = 3.0e38f;
    for (int v = tid; v < VN; v += 256) m = fminf(m, vt[v*3 + 1]);
    red[tid] = m;
    __syncthreads();
    for (int s = 128; s > 0; s >>= 1) {
        if (tid < s) red[tid] = fminf(red[tid], red[tid + s]);
        __syncthreads();
    }
    if (tid == 0) ws[Y_F] = -red[0];
}

// ---------------- kernel 3 ----------------
__global__ void k_jreg(const float* __restrict__ jr, const float* __restrict__ exprdirs,
                       float* __restrict__ ws)
{
    int j = blockIdx.x / 3, c = blockIdx.x % 3;
    int tid = threadIdx.x;
    const float* sdir = ws + SD_F;
    float acc[11];
    #pragma unroll
    for (int i = 0; i < 11; ++i) acc[i] = 0.f;
    for (int v = tid; v < VN; v += 256) {
        float w = jr[(size_t)j * VN + v];
        acc[10] += w * sdir[v*3 + c];
        const float* ed = exprdirs + (size_t)(v*3 + c) * 10;
        #pragma unroll
        for (int e = 0; e < 10; ++e) acc[e] += w * ed[e];
    }
    __shared__ float red[256];
    for (int i = 0; i < 11; ++i) {
        red[tid] = acc[i];
        __syncthreads();
        for (int s = 128; s > 0; s >>= 1) {
            if (tid < s) red[tid] += red[tid + s];
            __syncthreads();
        }
        if (tid == 0) {
            if (i == 10) ws[JS_F + j*3 + c] = red[0];
            else         ws[JE_F + (j*3 + c)*10 + i] = red[0];
        }
        __syncthreads();
    }
}

// ---------------- kernel 3b: lbs_weights -> packed frag-major ----------------
// layout: lwT[vt*1024 + ks*512 + (q*16 + lv)*8 + e] = lw[vt*16+lv][ks*32+q*8+e]
__global__ void k_lwT(const float* __restrict__ lw, f16* __restrict__ lwT)
{
    int t = threadIdx.x;
    int v  = blockIdx.x * 64 + (t >> 2);
    int jg = (t & 3) * 16;
    f16 tmp[16];
    #pragma unroll
    for (int jj = 0; jj < 16; ++jj) {
        int j = jg + jj;
        tmp[jj] = (f16)((v < VN && j < JN) ? lw[(size_t)v*JN + j] : 0.f);
    }
    int vt = v >> 4, lv = v & 15;
    int ks = jg >> 5, q0 = (jg >> 3) & 3;
    *(f16x8*)&lwT[(size_t)vt*1024 + ks*512 + (q0*16 + lv)*8]     = *(f16x8*)&tmp[0];
    *(f16x8*)&lwT[(size_t)vt*1024 + ks*512 + ((q0+1)*16 + lv)*8] = *(f16x8*)&tmp[8];
}

// ---------------- kernel 4: per-batch pose prep ----------------
// PFH packed: PFH[((b>>4)*16 + (k>>5))*512 + (((k>>3)&3)*16 + (b&15))*8 + (k&7)]
// AH  packed: AH[b*1024 + (j>>5)*512 + (((j>>3)&3)*16 + row)*8 + (j&7)]
__global__ void k_batch(const float* __restrict__ body, const float* __restrict__ hand,
                        const float* __restrict__ head, const float* __restrict__ expr,
                        const float* __restrict__ pelvis, const float* __restrict__ hand_mean,
                        const float* __restrict__ ws, f16* __restrict__ PFH,
                        f16* __restrict__ AH)
{
    int b = blockIdx.x, tid = threadIdx.x;
    __shared__ float rot[JN][9];
    __shared__ float jnt[JN][3];

    f16* AHb = AH + (size_t)b * 1024;
    #pragma unroll
    for (int i = 0; i < 16; ++i) AHb[tid + i*64] = (f16)0.f;

    if (tid < JN) {
        int j = tid;
        float r0, r1, r2;
        if (j == 0) {
            r0 = pelvis[b*3+0]; r1 = pelvis[b*3+1]; r2 = pelvis[b*3+2];
        } else if (j <= 21) {
            int o = b*63 + (j-1)*3;
            r0 = body[o]; r1 = body[o+1]; r2 = body[o+2];
        } else if (j <= 24) {
            int o = b*9 + (j-22)*3;
            r0 = head[o]; r1 = head[o+1]; r2 = head[o+2];
        } else {
            int h = (j-25)*3;
            r0 = hand[b*90+h+0] + hand_mean[h+0];
            r1 = hand[b*90+h+1] + hand_mean[h+1];
            r2 = hand[b*90+h+2] + hand_mean[h+2];
        }
        float a2  = r0*r0 + r1*r1 + r2*r2 + 1e-12f;
        float ang = sqrtf(a2);
        float inv = 1.0f / ang;
        float kx = r0*inv, ky = r1*inv, kz = r2*inv;
        float s = sinf(ang), c = cosf(ang), ic = 1.0f - c;
        rot[j][0] = c + ic*kx*kx;    rot[j][1] = ic*kx*ky - s*kz; rot[j][2] = ic*kx*kz + s*ky;
        rot[j][3] = ic*kx*ky + s*kz; rot[j][4] = c + ic*ky*ky;    rot[j][5] = ic*ky*kz - s*kx;
        rot[j][6] = ic*kx*kz - s*ky; rot[j][7] = ic*ky*kz + s*kx; rot[j][8] = c + ic*kz*kz;
        #pragma unroll
        for (int cc = 0; cc < 3; ++cc) {
            float acc = ws[JS_F + j*3 + cc];
            #pragma unroll
            for (int e = 0; e < 10; ++e)
                acc += expr[b*10 + e] * ws[JE_F + (j*3 + cc)*10 + e];
            jnt[j][cc] = acc;
        }
    }
    __syncthreads();

    // PFH row b (packed): [0..486) pose_feature | [486..496) expr | rest zero
    #pragma unroll
    for (int i = 0; i < 8; ++i) {
        int k = tid + i*64;
        float val = 0.f;
        if (k < 486) {
            int jj = k/9 + 1, ii = k%9;
            float d = (ii == 0 || ii == 4 || ii == 8) ? 1.0f : 0.0f;
            val = rot[jj][ii] - d;
        } else if (k < 496) {
            val = expr[b*10 + (k-486)];
        }
        PFH[(size_t)((b>>4)*16 + (k>>5))*512 + (((k>>3)&3)*16 + (b&15))*8 + (k&7)] = (f16)val;
    }

    // G chain: single wave, registers + shuffles, no barriers.
    int r = tid >> 2, cc = tid & 3;
    float g = 0.f;
    if (tid < 12) g = (cc < 3) ? rot[0][r*3 + cc] : jnt[0][r];
    for (int j = 0; j < JN; ++j) {
        if (j > 0) {
            float g0 = __shfl(g, r*4+0), g1 = __shfl(g, r*4+1);
            float g2 = __shfl(g, r*4+2), g3 = __shfl(g, r*4+3);
            if (cc < 3) g = g0*rot[j][cc] + g1*rot[j][3+cc] + g2*rot[j][6+cc];
            else        g = g0*(jnt[j][0]-jnt[j-1][0]) + g1*(jnt[j][1]-jnt[j-1][1])
                          + g2*(jnt[j][2]-jnt[j-1][2]) + g3;
        }
        float h0 = __shfl(g, r*4+0), h1 = __shfl(g, r*4+1), h2 = __shfl(g, r*4+2);
        float aval = g;
        if (cc == 3) aval = g - (h0*jnt[j][0] + h1*jnt[j][1] + h2*jnt[j][2]);
        if (tid < 12)
            AHb[(j>>5)*512 + (((j>>3)&3)*16 + tid)*8 + (j&7)] = (f16)aval;
    }
}

// ---------------- kernel 5: pose GEMM, swapped operands ----------------
// Block: 64 n-cols x 512 batches, K=512. A-frags from LDS pd-tile; B-frags
// coalesced from packed PFH (L2). No barriers in K-loop. Epilogue: LDS
// transpose -> f16x4 coalesced stores into VPH2[b][n] (width 31488).
#define BTS 520                     // pd tile row stride (halves)
#define LTS 72                      // epilogue L[b][c] stride (halves)
__global__ __launch_bounds__(256, 2) void k_pose(
    const float* __restrict__ pd, const float* __restrict__ ed,
    const float* __restrict__ ws, const f16* __restrict__ PFH,
    f16* __restrict__ VPH2)
{
    __shared__ f16 SH[BN*LTS];      // 36864 halves; pd-tile needs 64*520=33280
    __shared__ float SDl[64];
    const int t = threadIdx.x;
    const int n0 = blockIdx.x * 64;
    const int w = t >> 6, lane = t & 63, l = lane & 15, q = lane >> 4;
    f16* Bt = SH;

    {   // stage pd tile: f32 [k][n] -> f16 LDS [c][k]
        const int krow = t & 15, f = t >> 4;
        const int nb = n0 + f*4;
        #pragma unroll 4
        for (int it = 0; it < 32; ++it) {
            int k = krow + it*16;
            float4 vv = make_float4(0.f, 0.f, 0.f, 0.f);
            if (k < 486) {
                if (nb + 3 < VC3) vv = *(const float4*)(pd + (size_t)k*VC3 + nb);
                else {
                    float* pv = (float*)&vv;
                    for (int e = 0; e < 4; ++e)
                        if (nb + e < VC3) pv[e] = pd[(size_t)k*VC3 + nb + e];
                }
            } else if (k < 496) {
                float* pv = (float*)&vv;
                for (int e = 0; e < 4; ++e)
                    if (nb + e < VC3) pv[e] = ed[(size_t)(nb + e)*10 + (k - 486)];
            }
            int c = f*4;
            Bt[(c+0)*BTS + k] = (f16)vv.x;
            Bt[(c+1)*BTS + k] = (f16)vv.y;
            Bt[(c+2)*BTS + k] = (f16)vv.z;
            Bt[(c+3)*BTS + k] = (f16)vv.w;
        }
    }
    if (t < 64) { int n = n0 + t; SDl[t] = (n < VC3) ? ws[SD_F + n] : 0.f; }
    __syncthreads();

    f32x4 acc[4][8];
    #pragma unroll
    for (int i = 0; i < 4; ++i)
        #pragma unroll
        for (int j = 0; j < 8; ++j) acc[i][j] = (f32x4)0.f;

    for (int kc = 0; kc < 16; ++kc) {
        f16x8 af[4], bf[8];
        #pragma unroll
        for (int mt = 0; mt < 4; ++mt)
            af[mt] = *(const f16x8*)&Bt[(mt*16 + l)*BTS + kc*32 + q*8];
        #pragma unroll
        for (int nt = 0; nt < 8; ++nt)
            bf[nt] = *(const f16x8*)&PFH[(size_t)((w*8 + nt)*16 + kc)*512 + lane*8];
        #pragma unroll
        for (int mt = 0; mt < 4; ++mt)
            #pragma unroll
            for (int nt = 0; nt < 8; ++nt)
                acc[mt][nt] = __builtin_amdgcn_mfma_f32_16x16x32_f16(af[mt], bf[nt], acc[mt][nt], 0, 0, 0);
    }

    // epilogue: lane holds D[c = mt*16+q*4+i][b = w*128+nt*16+l]
    __syncthreads();                 // waves done reading Bt
    f16* L = SH;                     // [b][c] stride LTS
    #pragma unroll
    for (int mt = 0; mt < 4; ++mt)
        #pragma unroll
        for (int nt = 0; nt < 8; ++nt) {
            int b = w*128 + nt*16 + l;
            f16 pack[4];
            #pragma unroll
            for (int i = 0; i < 4; ++i) {
                int c = mt*16 + q*4 + i;
                pack[i] = (f16)(acc[mt][nt][i] + SDl[c]);
            }
            *(f16x4*)&L[b*LTS + mt*16 + q*4] = *(f16x4*)&pack[0];
        }
    __syncthreads();
    {   // coalesced f16x4 stores: 16 threads cover 64 cols, 16 b per pass
        const int c4 = (t & 15) * 4, bq = t >> 4;
        #pragma unroll 4
        for (int it = 0; it < 32; ++it) {
            int b = bq + 16*it;
            *(f16x4*)&VPH2[(size_t)b*NPAD + n0 + c4] = *(const f16x4*)&L[b*LTS + c4];
        }
    }
}

// ---------------- kernel 6: LBS GEMM + epilogue ----------------
// Block: 64 verts x 128 m2-rows (wave owns 32 m2 = 2 batches). A/B frag loads
// fully coalesced from packed AH / lwT. VPH2 slice (8 b x 192 halves = 3 KB)
// staged in LDS once per block. acc[2][4] = 32 VGPR -> target <=64 total.
__global__ __launch_bounds__(256, 8) void k_lbs(
    const float* __restrict__ gt, const float* __restrict__ ws,
    const f16* __restrict__ AH, const f16* __restrict__ lwT,
    const f16* __restrict__ VPH2, float* __restrict__ out)
{
    __shared__ f16 LV[8*192];
    const int t = threadIdx.x;
    const int v0 = blockIdx.x * 64;
    const int bbase = blockIdx.y * 8;
    const int w = t >> 6, lane = t & 63, l = lane & 15, q = lane >> 4;

    if (t < 192) {                  // stage VPH2 slice: 8 b x 384 B
        int bl = t / 24, c8 = t % 24;
        *(f16x8*)&LV[bl*192 + c8*8] =
            *(const f16x8*)&VPH2[(size_t)(bbase + bl)*NPAD + v0*3 + c8*8];
    }
    __syncthreads();

    f32x4 acc[2][4];
    #pragma unroll
    for (int i = 0; i < 2; ++i)
        #pragma unroll
        for (int j = 0; j < 4; ++j) acc[i][j] = (f32x4)0.f;

    #pragma unroll
    for (int ks = 0; ks < 2; ++ks) {
        f16x8 af[2], bf[4];
        #pragma unroll
        for (int nt = 0; nt < 4; ++nt)
            bf[nt] = *(const f16x8*)&lwT[(size_t)(blockIdx.x*4 + nt)*1024 + ks*512 + lane*8];
        #pragma unroll
        for (int mt = 0; mt < 2; ++mt)
            af[mt] = *(const f16x8*)&AH[(size_t)(bbase + w*2 + mt)*1024 + ks*512 + lane*8];
        #pragma unroll
        for (int mt = 0; mt < 2; ++mt)
            #pragma unroll
            for (int nt = 0; nt < 4; ++nt)
                acc[mt][nt] = __builtin_amdgcn_mfma_f32_16x16x32_f16(af[mt], bf[nt], acc[mt][nt], 0, 0, 0);
    }

    // lane (l,q) reg i: D[m2 = bbase*16 + w*32 + mt*16 + q*4 + i][v = v0 + nt*16 + l]
    //   => b = bbase + w*2 + mt, r = q, c = i
    float yoff = ws[Y_F];
    #pragma unroll
    for (int mt = 0; mt < 2; ++mt) {
        int b = bbase + w*2 + mt;
        float add = (q < 3) ? gt[b*3 + q] + (q == 1 ? yoff : 0.f) : 0.f;
        const f16* vrow = &LV[(w*2 + mt)*192];
        #pragma unroll
        for (int nt = 0; nt < 4; ++nt) {
            int v = v0 + nt*16 + l;
            if (q < 3 && v < VN) {
                int o = (nt*16 + l)*3;
                float vx = (float)vrow[o], vy = (float)vrow[o+1], vz = (float)vrow[o+2];
                f32x4 T = acc[mt][nt];
                out[((size_t)b*VN + v)*3 + q] = T[0]*vx + T[1]*vy + T[2]*vz + T[3] + add;
            }
        }
    }
}

extern "C" void kernel_launch(void* const* d_in, const int* in_sizes, int n_in,
                              void* d_out, int out_size, void* d_ws, size_t ws_size,
                              hipStream_t stream)
{
    const float* shape  = (const float*)d_in[0];
    const float* body   = (const float*)d_in[1];
    const float* hand   = (const float*)d_in[2];
    const float* head   = (const float*)d_in[3];
    const float* expr   = (const float*)d_in[4];
    const float* pelvis = (const float*)d_in[5];
    const float* gtrans = (const float*)d_in[6];
    const float* vt     = (const float*)d_in[7];
    const float* shdirs = (const float*)d_in[8];
    const float* exdirs = (const float*)d_in[9];
    const float* pdirs  = (const float*)d_in[10];
    const float* lbsw   = (const float*)d_in[11];
    const float* jreg   = (const float*)d_in[12];
    const float* hmean  = (const float*)d_in[13];
    float* wsf  = (float*)d_ws;
    f16*   PFH  = (f16*)((char*)d_ws + PFH_BYTE);
    f16*   AH   = (f16*)((char*)d_ws + AH_BYTE);
    f16*   VPH2 = (f16*)((char*)d_ws + VPH_BYTE);
    f16*   lwT  = (f16*)((char*)d_ws + LWT_BYTE);
    float* out  = (float*)d_out;

    hipLaunchKernelGGL(k_sdirs, dim3((VC3 + 255)/256), dim3(256), 0, stream,
                       vt, shdirs, shape, wsf);
    hipLaunchKernelGGL(k_ymin,  dim3(1),    dim3(256), 0, stream, vt, wsf);
    hipLaunchKernelGGL(k_jreg,  dim3(JN*3), dim3(256), 0, stream, jreg, exdirs, wsf);
    hipLaunchKernelGGL(k_lwT,   dim3(VPADV/64), dim3(256), 0, stream, lbsw, lwT);
    hipLaunchKernelGGL(k_batch, dim3(BN),   dim3(64),  0, stream,
                       body, hand, head, expr, pelvis, hmean, wsf, PFH, AH);
    hipLaunchKernelGGL(k_pose,  dim3(NPAD/64), dim3(256), 0, stream,
                       pdirs, exdirs, wsf, PFH, VPH2);
    hipLaunchKernelGGL(k_lbs,   dim3(VPADV/64, 8192/128), dim3(256), 0, stream,
                       gtrans, wsf, AH, lwT, VPH2, out);
}

// Round 2
// 246.289 us; speedup vs baseline: 1.2730x; 1.0865x over previous
//
#include <hip/hip_runtime.h>
#include <hip/hip_bf16.h>

// SMPL-X LBS forward. B=512, V=10475, J=55. f32 in/out; fp16 MFMA internally.
//
//  k_prep  : fused independent prep (one launch):
//            blocks [0,123)    s_dirs = v_template + shape.shapedirs
//            block  123        y_offset
//            blocks [124,288)  lwT packed MFMA-fragment-major [vtile][ks][lane][8]
//            blocks [288,453)  Js = Jreg@s_dirs (inline), JE = Jreg@exprdirs
//  k_batch : Rodrigues -> PFH packed; chain (shfl) -> AH packed [b][ks][lane][8]
//  k_pose  : D[n][b] = pdT_tile(LDS) x PFH(packed, coalesced); +s_dirs -> VPH2
//  k_lbs   : T = AH x lwT (packed coalesced frag loads); VPH2 slice in LDS;
//            epilogue staged in LDS -> monotonic contiguous f32 stores

typedef _Float16 f16;
typedef f16  f16x8 __attribute__((ext_vector_type(8)));
typedef f16  f16x4 __attribute__((ext_vector_type(4)));
typedef float f32x4 __attribute__((ext_vector_type(4)));

#define VN    10475
#define JN    55
#define BN    512
#define VC3   31425
#define NPAD  31488          // 492*64
#define VPADV 10496

// f32 ws region (float offsets):
#define SD_F  0              // s_dirs [VC3]
#define JS_F  31425          // [165]
#define JE_F  31590          // [1650]
#define Y_F   33240
// byte offsets:
#define PFH_BYTE  (160*1024)           // f16 packed [32][16][64][8]  = 512 KB
#define AH_BYTE   (768*1024)           // f16 packed [512][2][64][8]  = 1 MB
#define VPH_BYTE  (2*1024*1024)        // f16 [512][31488] = 30.75 MB
#define LWT_BYTE  (34*1024*1024)       // f16 packed [656][2][64][8]  = 1.3 MB

// prep block ranges
#define NB_SD   123
#define NB_LWT  164
#define NB_JREG 165
#define NB_PREP (NB_SD + 1 + NB_LWT + NB_JREG)   // 453

// ---------------- kernel 1: fused prep ----------------
__global__ __launch_bounds__(256) void k_prep(
    const float* __restrict__ vt, const float* __restrict__ shapedirs,
    const float* __restrict__ shape, const float* __restrict__ lw,
    const float* __restrict__ jr, const float* __restrict__ exprdirs,
    float* __restrict__ ws, f16* __restrict__ lwT)
{
    __shared__ float red[256];
    const int bb  = blockIdx.x;
    const int tid = threadIdx.x;

    if (bb < NB_SD) {
        // ---- s_dirs ----
        int i = bb * 256 + tid;
        if (i < VC3) {
            float acc = vt[i];
            const float* sd = shapedirs + (size_t)i * 10;
            #pragma unroll
            for (int s = 0; s < 10; ++s) acc += shape[s] * sd[s];
            ws[SD_F + i] = acc;
        }
    } else if (bb == NB_SD) {
        // ---- y_offset ----
        float m = 3.0e38f;
        for (int v = tid; v < VN; v += 256) m = fminf(m, vt[v*3 + 1]);
        red[tid] = m;
        __syncthreads();
        for (int s = 128; s > 0; s >>= 1) {
            if (tid < s) red[tid] = fminf(red[tid], red[tid + s]);
            __syncthreads();
        }
        if (tid == 0) ws[Y_F] = -red[0];
    } else if (bb < NB_SD + 1 + NB_LWT) {
        // ---- lwT packed: lwT[vt*1024 + ks*512 + (q*16 + lv)*8 + e] ----
        int bx = bb - (NB_SD + 1);
        int v  = bx * 64 + (tid >> 2);
        int jg = (tid & 3) * 16;
        f16 tmp[16];
        #pragma unroll
        for (int jj = 0; jj < 16; ++jj) {
            int j = jg + jj;
            tmp[jj] = (f16)((v < VN && j < JN) ? lw[(size_t)v*JN + j] : 0.f);
        }
        int vtile = v >> 4, lv = v & 15;
        int ks = jg >> 5, q0 = (jg >> 3) & 3;
        *(f16x8*)&lwT[(size_t)vtile*1024 + ks*512 + (q0*16 + lv)*8]     = *(f16x8*)&tmp[0];
        *(f16x8*)&lwT[(size_t)vtile*1024 + ks*512 + ((q0+1)*16 + lv)*8] = *(f16x8*)&tmp[8];
    } else {
        // ---- jreg (s_dirs recomputed inline -> no dep on s_dirs blocks) ----
        int jb = bb - (NB_SD + 1 + NB_LWT);
        int j = jb / 3, c = jb % 3;
        float acc[11];
        #pragma unroll
        for (int i = 0; i < 11; ++i) acc[i] = 0.f;
        for (int v = tid; v < VN; v += 256) {
            float w = jr[(size_t)j * VN + v];
            float sv = vt[v*3 + c];
            const float* sd = shapedirs + (size_t)(v*3 + c) * 10;
            #pragma unroll
            for (int s = 0; s < 10; ++s) sv += shape[s] * sd[s];
            acc[10] += w * sv;
            const float* ed = exprdirs + (size_t)(v*3 + c) * 10;
            #pragma unroll
            for (int e = 0; e < 10; ++e) acc[e] += w * ed[e];
        }
        for (int i = 0; i < 11; ++i) {
            red[tid] = acc[i];
            __syncthreads();
            for (int s = 128; s > 0; s >>= 1) {
                if (tid < s) red[tid] += red[tid + s];
                __syncthreads();
            }
            if (tid == 0) {
                if (i == 10) ws[JS_F + j*3 + c] = red[0];
                else         ws[JE_F + (j*3 + c)*10 + i] = red[0];
            }
            __syncthreads();
        }
    }
}

// ---------------- kernel 2: per-batch pose prep ----------------
// PFH packed: PFH[((b>>4)*16 + (k>>5))*512 + (((k>>3)&3)*16 + (b&15))*8 + (k&7)]
// AH  packed: AH[b*1024 + (j>>5)*512 + (((j>>3)&3)*16 + row)*8 + (j&7)]
__global__ void k_batch(const float* __restrict__ body, const float* __restrict__ hand,
                        const float* __restrict__ head, const float* __restrict__ expr,
                        const float* __restrict__ pelvis, const float* __restrict__ hand_mean,
                        const float* __restrict__ ws, f16* __restrict__ PFH,
                        f16* __restrict__ AH)
{
    int b = blockIdx.x, tid = threadIdx.x;
    __shared__ float rot[JN][9];
    __shared__ float jnt[JN][3];

    f16* AHb = AH + (size_t)b * 1024;
    #pragma unroll
    for (int i = 0; i < 16; ++i) AHb[tid + i*64] = (f16)0.f;

    if (tid < JN) {
        int j = tid;
        float r0, r1, r2;
        if (j == 0) {
            r0 = pelvis[b*3+0]; r1 = pelvis[b*3+1]; r2 = pelvis[b*3+2];
        } else if (j <= 21) {
            int o = b*63 + (j-1)*3;
            r0 = body[o]; r1 = body[o+1]; r2 = body[o+2];
        } else if (j <= 24) {
            int o = b*9 + (j-22)*3;
            r0 = head[o]; r1 = head[o+1]; r2 = head[o+2];
        } else {
            int h = (j-25)*3;
            r0 = hand[b*90+h+0] + hand_mean[h+0];
            r1 = hand[b*90+h+1] + hand_mean[h+1];
            r2 = hand[b*90+h+2] + hand_mean[h+2];
        }
        float a2  = r0*r0 + r1*r1 + r2*r2 + 1e-12f;
        float ang = sqrtf(a2);
        float inv = 1.0f / ang;
        float kx = r0*inv, ky = r1*inv, kz = r2*inv;
        float s = sinf(ang), c = cosf(ang), ic = 1.0f - c;
        rot[j][0] = c + ic*kx*kx;    rot[j][1] = ic*kx*ky - s*kz; rot[j][2] = ic*kx*kz + s*ky;
        rot[j][3] = ic*kx*ky + s*kz; rot[j][4] = c + ic*ky*ky;    rot[j][5] = ic*ky*kz - s*kx;
        rot[j][6] = ic*kx*kz - s*ky; rot[j][7] = ic*ky*kz + s*kx; rot[j][8] = c + ic*kz*kz;
        #pragma unroll
        for (int cc = 0; cc < 3; ++cc) {
            float acc = ws[JS_F + j*3 + cc];
            #pragma unroll
            for (int e = 0; e < 10; ++e)
                acc += expr[b*10 + e] * ws[JE_F + (j*3 + cc)*10 + e];
            jnt[j][cc] = acc;
        }
    }
    __syncthreads();

    // PFH row b (packed): [0..486) pose_feature | [486..496) expr | rest zero
    #pragma unroll
    for (int i = 0; i < 8; ++i) {
        int k = tid + i*64;
        float val = 0.f;
        if (k < 486) {
            int jj = k/9 + 1, ii = k%9;
            float d = (ii == 0 || ii == 4 || ii == 8) ? 1.0f : 0.0f;
            val = rot[jj][ii] - d;
        } else if (k < 496) {
            val = expr[b*10 + (k-486)];
        }
        PFH[(size_t)((b>>4)*16 + (k>>5))*512 + (((k>>3)&3)*16 + (b&15))*8 + (k&7)] = (f16)val;
    }

    // G chain: single wave, registers + shuffles, no barriers.
    int r = tid >> 2, cc = tid & 3;
    float g = 0.f;
    if (tid < 12) g = (cc < 3) ? rot[0][r*3 + cc] : jnt[0][r];
    for (int j = 0; j < JN; ++j) {
        if (j > 0) {
            float g0 = __shfl(g, r*4+0), g1 = __shfl(g, r*4+1);
            float g2 = __shfl(g, r*4+2), g3 = __shfl(g, r*4+3);
            if (cc < 3) g = g0*rot[j][cc] + g1*rot[j][3+cc] + g2*rot[j][6+cc];
            else        g = g0*(jnt[j][0]-jnt[j-1][0]) + g1*(jnt[j][1]-jnt[j-1][1])
                          + g2*(jnt[j][2]-jnt[j-1][2]) + g3;
        }
        float h0 = __shfl(g, r*4+0), h1 = __shfl(g, r*4+1), h2 = __shfl(g, r*4+2);
        float aval = g;
        if (cc == 3) aval = g - (h0*jnt[j][0] + h1*jnt[j][1] + h2*jnt[j][2]);
        if (tid < 12)
            AHb[(j>>5)*512 + (((j>>3)&3)*16 + tid)*8 + (j&7)] = (f16)aval;
    }
}

// ---------------- kernel 3: pose GEMM, swapped operands ----------------
#define BTS 520                     // pd tile row stride (halves)
#define LTS 72                      // epilogue L[b][c] stride (halves)
__global__ __launch_bounds__(256, 2) void k_pose(
    const float* __restrict__ pd, const float* __restrict__ ed,
    const float* __restrict__ ws, const f16* __restrict__ PFH,
    f16* __restrict__ VPH2)
{
    __shared__ f16 SH[BN*LTS];      // 36864 halves; pd-tile needs 64*520=33280
    __shared__ float SDl[64];
    const int t = threadIdx.x;
    const int n0 = blockIdx.x * 64;
    const int w = t >> 6, lane = t & 63, l = lane & 15, q = lane >> 4;
    f16* Bt = SH;

    if (t < 64) { int n = n0 + t; SDl[t] = (n < VC3) ? ws[SD_F + n] : 0.f; }

    {   // stage pd tile: f32 [k][n] -> f16 LDS [c][k]
        const int krow = t & 15, f = t >> 4;
        const int nb = n0 + f*4;
        #pragma unroll 8
        for (int it = 0; it < 32; ++it) {
            int k = krow + it*16;
            float4 vv = make_float4(0.f, 0.f, 0.f, 0.f);
            if (k < 486) {
                if (nb + 3 < VC3) vv = *(const float4*)(pd + (size_t)k*VC3 + nb);
                else {
                    float* pv = (float*)&vv;
                    for (int e = 0; e < 4; ++e)
                        if (nb + e < VC3) pv[e] = pd[(size_t)k*VC3 + nb + e];
                }
            } else if (k < 496) {
                float* pv = (float*)&vv;
                for (int e = 0; e < 4; ++e)
                    if (nb + e < VC3) pv[e] = ed[(size_t)(nb + e)*10 + (k - 486)];
            }
            int c = f*4;
            Bt[(c+0)*BTS + k] = (f16)vv.x;
            Bt[(c+1)*BTS + k] = (f16)vv.y;
            Bt[(c+2)*BTS + k] = (f16)vv.z;
            Bt[(c+3)*BTS + k] = (f16)vv.w;
        }
    }
    __syncthreads();

    f32x4 acc[4][8];
    #pragma unroll
    for (int i = 0; i < 4; ++i)
        #pragma unroll
        for (int j = 0; j < 8; ++j) acc[i][j] = (f32x4)0.f;

    for (int kc = 0; kc < 16; ++kc) {
        f16x8 af[4], bf[8];
        #pragma unroll
        for (int mt = 0; mt < 4; ++mt)
            af[mt] = *(const f16x8*)&Bt[(mt*16 + l)*BTS + kc*32 + q*8];
        #pragma unroll
        for (int nt = 0; nt < 8; ++nt)
            bf[nt] = *(const f16x8*)&PFH[(size_t)((w*8 + nt)*16 + kc)*512 + lane*8];
        #pragma unroll
        for (int mt = 0; mt < 4; ++mt)
            #pragma unroll
            for (int nt = 0; nt < 8; ++nt)
                acc[mt][nt] = __builtin_amdgcn_mfma_f32_16x16x32_f16(af[mt], bf[nt], acc[mt][nt], 0, 0, 0);
    }

    // epilogue: lane holds D[c = mt*16+q*4+i][b = w*128+nt*16+l]
    __syncthreads();                 // waves done reading Bt
    f16* L = SH;                     // [b][c] stride LTS
    #pragma unroll
    for (int mt = 0; mt < 4; ++mt)
        #pragma unroll
        for (int nt = 0; nt < 8; ++nt) {
            int b = w*128 + nt*16 + l;
            f16 pack[4];
            #pragma unroll
            for (int i = 0; i < 4; ++i) {
                int c = mt*16 + q*4 + i;
                pack[i] = (f16)(acc[mt][nt][i] + SDl[c]);
            }
            *(f16x4*)&L[b*LTS + mt*16 + q*4] = *(f16x4*)&pack[0];
        }
    __syncthreads();
    {   // coalesced f16x4 stores: 16 threads cover 64 cols, 16 b per pass
        const int c4 = (t & 15) * 4, bq = t >> 4;
        #pragma unroll 4
        for (int it = 0; it < 32; ++it) {
            int b = bq + 16*it;
            *(f16x4*)&VPH2[(size_t)b*NPAD + n0 + c4] = *(const f16x4*)&L[b*LTS + c4];
        }
    }
}

// ---------------- kernel 4: LBS GEMM + epilogue ----------------
// Block: 64 verts x 128 m2-rows (wave owns 32 m2 = 2 batches). A/B frag loads
// fully coalesced from packed AH / lwT. VPH2 slice staged in LDS. Output
// staged in LDS then written with monotonic contiguous dword stores
// (full-line coverage -> no write amplification).
__global__ __launch_bounds__(256, 8) void k_lbs(
    const float* __restrict__ gt, const float* __restrict__ ws,
    const f16* __restrict__ AH, const f16* __restrict__ lwT,
    const f16* __restrict__ VPH2, float* __restrict__ out)
{
    __shared__ f16   LV[8*192];      // 3 KB
    __shared__ float OUTS[8*192];    // 6 KB
    const int t = threadIdx.x;
    const int v0 = blockIdx.x * 64;
    const int bbase = blockIdx.y * 8;
    const int w = t >> 6, lane = t & 63, l = lane & 15, q = lane >> 4;

    if (t < 192) {                  // stage VPH2 slice: 8 b x 384 B
        int bl = t / 24, c8 = t % 24;
        *(f16x8*)&LV[bl*192 + c8*8] =
            *(const f16x8*)&VPH2[(size_t)(bbase + bl)*NPAD + v0*3 + c8*8];
    }
    __syncthreads();

    f32x4 acc[2][4];
    #pragma unroll
    for (int i = 0; i < 2; ++i)
        #pragma unroll
        for (int j = 0; j < 4; ++j) acc[i][j] = (f32x4)0.f;

    #pragma unroll
    for (int ks = 0; ks < 2; ++ks) {
        f16x8 af[2], bf[4];
        #pragma unroll
        for (int nt = 0; nt < 4; ++nt)
            bf[nt] = *(const f16x8*)&lwT[(size_t)(blockIdx.x*4 + nt)*1024 + ks*512 + lane*8];
        #pragma unroll
        for (int mt = 0; mt < 2; ++mt)
            af[mt] = *(const f16x8*)&AH[(size_t)(bbase + w*2 + mt)*1024 + ks*512 + lane*8];
        #pragma unroll
        for (int mt = 0; mt < 2; ++mt)
            #pragma unroll
            for (int nt = 0; nt < 4; ++nt)
                acc[mt][nt] = __builtin_amdgcn_mfma_f32_16x16x32_f16(af[mt], bf[nt], acc[mt][nt], 0, 0, 0);
    }

    // lane (l,q) reg i: D[m2][v = v0 + nt*16 + l] => b = bbase + w*2 + mt, r=q, c=i
    float yoff = ws[Y_F];
    #pragma unroll
    for (int mt = 0; mt < 2; ++mt) {
        int bl = w*2 + mt;
        float add = 0.f;
        if (q < 3) add = gt[(bbase + bl)*3 + q] + (q == 1 ? yoff : 0.f);
        const f16* vrow = &LV[bl*192];
        #pragma unroll
        for (int nt = 0; nt < 4; ++nt) {
            if (q < 3) {
                int o = (nt*16 + l)*3;
                float vx = (float)vrow[o], vy = (float)vrow[o+1], vz = (float)vrow[o+2];
                f32x4 T = acc[mt][nt];
                OUTS[bl*192 + o + q] = T[0]*vx + T[1]*vy + T[2]*vz + T[3] + add;
            }
        }
    }
    __syncthreads();
    // monotonic contiguous stores: thread t writes ascending dwords
    #pragma unroll
    for (int pass = 0; pass < 6; ++pass) {
        int idx = pass*256 + t;            // 0..1535
        int bl  = idx / 192;
        int c   = idx - bl*192;
        if (v0*3 + c < VC3)                // VN*3 == VC3
            out[(size_t)(bbase + bl)*VC3 + v0*3 + c] = OUTS[idx];
    }
}

extern "C" void kernel_launch(void* const* d_in, const int* in_sizes, int n_in,
                              void* d_out, int out_size, void* d_ws, size_t ws_size,
                              hipStream_t stream)
{
    const float* shape  = (const float*)d_in[0];
    const float* body   = (const float*)d_in[1];
    const float* hand   = (const float*)d_in[2];
    const float* head   = (const float*)d_in[3];
    const float* expr   = (const float*)d_in[4];
    const float* pelvis = (const float*)d_in[5];
    const float* gtrans = (const float*)d_in[6];
    const float* vt     = (const float*)d_in[7];
    const float* shdirs = (const float*)d_in[8];
    const float* exdirs = (const float*)d_in[9];
    const float* pdirs  = (const float*)d_in[10];
    const float* lbsw   = (const float*)d_in[11];
    const float* jreg   = (const float*)d_in[12];
    const float* hmean  = (const float*)d_in[13];
    float* wsf  = (float*)d_ws;
    f16*   PFH  = (f16*)((char*)d_ws + PFH_BYTE);
    f16*   AH   = (f16*)((char*)d_ws + AH_BYTE);
    f16*   VPH2 = (f16*)((char*)d_ws + VPH_BYTE);
    f16*   lwT  = (f16*)((char*)d_ws + LWT_BYTE);
    float* out  = (float*)d_out;

    hipLaunchKernelGGL(k_prep,  dim3(NB_PREP), dim3(256), 0, stream,
                       vt, shdirs, shape, lbsw, jreg, exdirs, wsf, lwT);
    hipLaunchKernelGGL(k_batch, dim3(BN),   dim3(64),  0, stream,
                       body, hand, head, expr, pelvis, hmean, wsf, PFH, AH);
    hipLaunchKernelGGL(k_pose,  dim3(NPAD/64), dim3(256), 0, stream,
                       pdirs, exdirs, wsf, PFH, VPH2);
    hipLaunchKernelGGL(k_lbs,   dim3(VPADV/64, 8192/128), dim3(256), 0, stream,
                       gtrans, wsf, AH, lwT, VPH2, out);
}